// Round 1
// baseline (790.341 us; speedup 1.0000x reference)
//
#include <hip/hip_runtime.h>

#define OUT_F 11008
#define IN_F  4096
#define M_TOT 4096   // 2*2048
#define BK    32

typedef __bf16 bf16;
typedef __attribute__((ext_vector_type(8))) __bf16 bf16x8;
typedef __attribute__((ext_vector_type(4))) float  floatx4;

// async global->LDS, 16B per lane. LDS dest is wave-uniform base + lane*16:
// we always pass lds = base + tid*16 so every wave's lanes are contiguous.
#define GLD_LDS16(g, l) __builtin_amdgcn_global_load_lds(                      \
    (const __attribute__((address_space(1))) unsigned int*)(g),                \
    (__attribute__((address_space(3))) unsigned int*)(l), 16, 0, 0)

// ---------------- pre-pass 1: dequant W to bf16 ----------------
// one thread per 8 consecutive in-features (8 | 128 so one scale per thread)
__global__ __launch_bounds__(256) void dequant_w_kernel(
    const int* __restrict__ qw, const float* __restrict__ sc,
    bf16* __restrict__ w) {
  const int idx  = blockIdx.x * 256 + threadIdx.x;   // [0, OUT_F*IN_F/8)
  const int o    = idx >> 9;            // / (IN_F/8 = 512)
  const int iv   = idx & 511;           // vector index within row
  const float s  = sc[o * (IN_F / 128) + (iv >> 4)]; // group = (iv*8)>>7
  const int base = idx * 8;
  const int4* p  = (const int4*)(qw + base);
  const int4 q0  = p[0];
  const int4 q1  = p[1];
  bf16x8 v;
  v[0] = (bf16)((float)q0.x * s);
  v[1] = (bf16)((float)q0.y * s);
  v[2] = (bf16)((float)q0.z * s);
  v[3] = (bf16)((float)q0.w * s);
  v[4] = (bf16)((float)q1.x * s);
  v[5] = (bf16)((float)q1.y * s);
  v[6] = (bf16)((float)q1.z * s);
  v[7] = (bf16)((float)q1.w * s);
  *(bf16x8*)(w + base) = v;
}

// ---------------- pre-pass 2: cast x to bf16 ----------------
__global__ __launch_bounds__(256) void cast_x_kernel(
    const float* __restrict__ x, bf16* __restrict__ xb) {
  const int idx  = blockIdx.x * 256 + threadIdx.x;
  const int base = idx * 8;
  const float4* p = (const float4*)(x + base);
  const float4 a = p[0];
  const float4 b = p[1];
  bf16x8 v;
  v[0] = (bf16)a.x; v[1] = (bf16)a.y; v[2] = (bf16)a.z; v[3] = (bf16)a.w;
  v[4] = (bf16)b.x; v[5] = (bf16)b.y; v[6] = (bf16)b.z; v[7] = (bf16)b.w;
  *(bf16x8*)(xb + base) = v;
}

// ---------------- GEMM: C[M][N] = A[M][K] * B[N][K]^T + bias ----------------
// m97 structure: 128x128 tile, BK=32, 256 threads (4 waves, 2x2), each wave
// 64x64 = 4x4 tiles of v_mfma_f32_16x16x32_bf16; global_load_lds width=16.
__global__ __launch_bounds__(256) void gemm_bt_bias_kernel(
    const bf16* __restrict__ A, const bf16* __restrict__ B,
    const float* __restrict__ bias, float* __restrict__ C) {
  __shared__ bf16 As[128 * BK];   // 8 KB, row-major [128][32], no pad
  __shared__ bf16 Bs[128 * BK];   // (global_load_lds forbids padding)

  const int t    = threadIdx.x;
  const int bm   = blockIdx.x * 128;
  const int bn   = blockIdx.y * 128;
  const int lane = t & 63;
  const int wv   = t >> 6;
  const int wm   = (wv >> 1) * 64;       // wave sub-tile origin (M)
  const int wn   = (wv & 1) * 64;        // wave sub-tile origin (N)
  const int lr   = lane & 15;            // A row / B col within 16
  const int lk   = (lane >> 4) * 8;      // k offset within 32

  // staging: thread t stages tile elements [t*8, t*8+8) (row-major [128][32])
  // inst0 -> rows 0..63, inst1 -> rows 64..127
  const int r0 = t >> 2;
  const int c0 = (t & 3) * 8;
  const bf16* gA0 = A + (bm + r0) * IN_F + c0;
  const bf16* gA1 = A + (bm + 64 + r0) * IN_F + c0;
  const bf16* gB0 = B + (bn + r0) * IN_F + c0;
  const bf16* gB1 = B + (bn + 64 + r0) * IN_F + c0;
  bf16* lA0 = &As[t * 8];
  bf16* lA1 = &As[2048 + t * 8];
  bf16* lB0 = &Bs[t * 8];
  bf16* lB1 = &Bs[2048 + t * 8];

  floatx4 acc[4][4];
#pragma unroll
  for (int i = 0; i < 4; i++)
#pragma unroll
    for (int j = 0; j < 4; j++)
      acc[i][j] = (floatx4){0.f, 0.f, 0.f, 0.f};

  for (int kt = 0; kt < IN_F; kt += BK) {
    GLD_LDS16(gA0 + kt, lA0);
    GLD_LDS16(gA1 + kt, lA1);
    GLD_LDS16(gB0 + kt, lB0);
    GLD_LDS16(gB1 + kt, lB1);
    __syncthreads();   // compiler emits s_waitcnt vmcnt(0) before s_barrier

    bf16x8 af[4], bfr[4];
#pragma unroll
    for (int i = 0; i < 4; i++)
      af[i] = *(const bf16x8*)&As[(wm + i * 16 + lr) * BK + lk];
#pragma unroll
    for (int j = 0; j < 4; j++)
      bfr[j] = *(const bf16x8*)&Bs[(wn + j * 16 + lr) * BK + lk];

#pragma unroll
    for (int i = 0; i < 4; i++)
#pragma unroll
      for (int j = 0; j < 4; j++)
        acc[i][j] = __builtin_amdgcn_mfma_f32_16x16x32_bf16(
            af[i], bfr[j], acc[i][j], 0, 0, 0);

    __syncthreads();   // all LDS reads done before next overwrite
  }

  // epilogue: C/D layout col = lane&15, row = (lane>>4)*4 + reg
#pragma unroll
  for (int j = 0; j < 4; j++) {
    const int col = bn + wn + j * 16 + lr;
    const float bv = bias[col];
#pragma unroll
    for (int i = 0; i < 4; i++) {
      const int row0 = bm + wm + i * 16 + (lane >> 4) * 4;
#pragma unroll
      for (int r = 0; r < 4; r++)
        C[(row0 + r) * OUT_F + col] = acc[i][j][r] + bv;
    }
  }
}

extern "C" void kernel_launch(void* const* d_in, const int* in_sizes, int n_in,
                              void* d_out, int out_size, void* d_ws, size_t ws_size,
                              hipStream_t stream) {
  const float* x    = (const float*)d_in[0];  // [2,2048,4096] fp32
  const int*   qw   = (const int*)d_in[1];    // [11008,4096] int32 in [-8,7]
  const float* sc   = (const float*)d_in[2];  // [11008,32] fp32
  const float* bias = (const float*)d_in[3];  // [11008] fp32
  float* out = (float*)d_out;                 // [2,2048,11008] fp32

  // workspace layout: W_bf16 (90.2 MB) then X_bf16 (33.6 MB); ~124 MB total
  bf16* wq = (bf16*)d_ws;
  bf16* xb = (bf16*)((char*)d_ws + (size_t)OUT_F * IN_F * sizeof(bf16));

  dequant_w_kernel<<<(OUT_F * IN_F / 8) / 256, 256, 0, stream>>>(qw, sc, wq);
  cast_x_kernel<<<(M_TOT * IN_F / 8) / 256, 256, 0, stream>>>(x, xb);

  dim3 grid(M_TOT / 128, OUT_F / 128);  // 32 x 86
  gemm_bt_bias_kernel<<<grid, 256, 0, stream>>>(xb, wq, bias, out);
}

// Round 2
// 748.152 us; speedup vs baseline: 1.0564x; 1.0564x over previous
//
#include <hip/hip_runtime.h>

#define OUT_F 11008
#define IN_F  4096
#define M_TOT 4096   // 2*2048
#define BM    128
#define BN    256
#define BK    32

typedef __bf16 bf16;
typedef __attribute__((ext_vector_type(8))) __bf16 bf16x8;
typedef __attribute__((ext_vector_type(4))) float  floatx4;

// async global->LDS, 16B per lane; LDS dest = wave-uniform base + lane*16.
#define GLD_LDS16(g, l) __builtin_amdgcn_global_load_lds(                      \
    (const __attribute__((address_space(1))) unsigned int*)(g),                \
    (__attribute__((address_space(3))) unsigned int*)(l), 16, 0, 0)

// ---------------- pre-pass 1: dequant W to bf16 ----------------
__global__ __launch_bounds__(256) void dequant_w_kernel(
    const int* __restrict__ qw, const float* __restrict__ sc,
    bf16* __restrict__ w) {
  const int idx  = blockIdx.x * 256 + threadIdx.x;   // [0, OUT_F*IN_F/8)
  const int o    = idx >> 9;            // / (IN_F/8 = 512)
  const int iv   = idx & 511;           // vector index within row
  const float s  = sc[o * (IN_F / 128) + (iv >> 4)]; // group = (iv*8)>>7
  const int base = idx * 8;
  const int4* p  = (const int4*)(qw + base);
  const int4 q0  = p[0];
  const int4 q1  = p[1];
  bf16x8 v;
  v[0] = (bf16)((float)q0.x * s);
  v[1] = (bf16)((float)q0.y * s);
  v[2] = (bf16)((float)q0.z * s);
  v[3] = (bf16)((float)q0.w * s);
  v[4] = (bf16)((float)q1.x * s);
  v[5] = (bf16)((float)q1.y * s);
  v[6] = (bf16)((float)q1.z * s);
  v[7] = (bf16)((float)q1.w * s);
  *(bf16x8*)(w + base) = v;
}

// ---------------- pre-pass 2: cast x to bf16 ----------------
__global__ __launch_bounds__(256) void cast_x_kernel(
    const float* __restrict__ x, bf16* __restrict__ xb) {
  const int idx  = blockIdx.x * 256 + threadIdx.x;
  const int base = idx * 8;
  const float4* p = (const float4*)(x + base);
  const float4 a = p[0];
  const float4 b = p[1];
  bf16x8 v;
  v[0] = (bf16)a.x; v[1] = (bf16)a.y; v[2] = (bf16)a.z; v[3] = (bf16)a.w;
  v[4] = (bf16)b.x; v[5] = (bf16)b.y; v[6] = (bf16)b.z; v[7] = (bf16)b.w;
  *(bf16x8*)(xb + base) = v;
}

// ---------------- GEMM: C[M][N] = A[M][K] * B[N][K]^T + bias ----------------
// Block tile 128x256, BK=32, 256 threads = 4 waves in 2x2; each wave computes
// 64x128 via 4x8 tiles of v_mfma_f32_16x16x32_bf16 (128 acc VGPRs/lane).
// FLOP per LDS byte = 42.7 (vs 32 at 64x64 wave tile) -> MFMA-bound balance.
__global__ __launch_bounds__(256, 2) void gemm_bt_bias_kernel(
    const bf16* __restrict__ A, const bf16* __restrict__ B,
    const float* __restrict__ bias, float* __restrict__ C) {
  __shared__ bf16 As[BM * BK];   // 8 KB row-major [128][32] (no pad: GLD-LDS)
  __shared__ bf16 Bs[BN * BK];   // 16 KB row-major [256][32]

  const int t    = threadIdx.x;
  const int bm   = blockIdx.x * BM;
  const int bn   = blockIdx.y * BN;
  const int lane = t & 63;
  const int wv   = t >> 6;
  const int wm   = (wv >> 1) * 64;       // wave sub-tile origin (M): 0/64
  const int wn   = (wv & 1) * 128;       // wave sub-tile origin (N): 0/128
  const int lr   = lane & 15;            // frag row/col within 16
  const int lk   = (lane >> 4) * 8;      // frag k offset within 32

  // staging slot s covers LDS bytes [s*16, s*16+16): row = s>>2, col8 = s&3
  const int r0 = t >> 2;
  const int c0 = (t & 3) * 8;
  const bf16* gA0 = A + (bm + r0) * IN_F + c0;          // slots t
  const bf16* gA1 = A + (bm + 64 + r0) * IN_F + c0;     // slots t+256
  const bf16* gB0 = B + (bn + r0) * IN_F + c0;          // slots t
  const bf16* gB1 = B + (bn + 64 + r0) * IN_F + c0;     // +256
  const bf16* gB2 = B + (bn + 128 + r0) * IN_F + c0;    // +512
  const bf16* gB3 = B + (bn + 192 + r0) * IN_F + c0;    // +768
  bf16* lA0 = &As[t * 8];
  bf16* lA1 = &As[2048 + t * 8];
  bf16* lB0 = &Bs[t * 8];
  bf16* lB1 = &Bs[2048 + t * 8];
  bf16* lB2 = &Bs[4096 + t * 8];
  bf16* lB3 = &Bs[6144 + t * 8];

  floatx4 acc[4][8];
#pragma unroll
  for (int i = 0; i < 4; i++)
#pragma unroll
    for (int j = 0; j < 8; j++)
      acc[i][j] = (floatx4){0.f, 0.f, 0.f, 0.f};

  for (int kt = 0; kt < IN_F; kt += BK) {
    GLD_LDS16(gA0 + kt, lA0);
    GLD_LDS16(gA1 + kt, lA1);
    GLD_LDS16(gB0 + kt, lB0);
    GLD_LDS16(gB1 + kt, lB1);
    GLD_LDS16(gB2 + kt, lB2);
    GLD_LDS16(gB3 + kt, lB3);
    __syncthreads();

    bf16x8 af[4], bfr[8];
#pragma unroll
    for (int i = 0; i < 4; i++)
      af[i] = *(const bf16x8*)&As[(wm + i * 16 + lr) * BK + lk];
#pragma unroll
    for (int j = 0; j < 8; j++)
      bfr[j] = *(const bf16x8*)&Bs[(wn + j * 16 + lr) * BK + lk];

#pragma unroll
    for (int i = 0; i < 4; i++)
#pragma unroll
      for (int j = 0; j < 8; j++)
        acc[i][j] = __builtin_amdgcn_mfma_f32_16x16x32_bf16(
            af[i], bfr[j], acc[i][j], 0, 0, 0);

    __syncthreads();
  }

  // epilogue: C/D layout col = lane&15, row = (lane>>4)*4 + reg
#pragma unroll
  for (int j = 0; j < 8; j++) {
    const int col = bn + wn + j * 16 + lr;
    const float bv = bias[col];
#pragma unroll
    for (int i = 0; i < 4; i++) {
      const int row0 = bm + wm + i * 16 + (lane >> 4) * 4;
#pragma unroll
      for (int r = 0; r < 4; r++)
        __builtin_nontemporal_store(acc[i][j][r] + bv,
                                    &C[(row0 + r) * OUT_F + col]);
    }
  }
}

extern "C" void kernel_launch(void* const* d_in, const int* in_sizes, int n_in,
                              void* d_out, int out_size, void* d_ws, size_t ws_size,
                              hipStream_t stream) {
  const float* x    = (const float*)d_in[0];  // [2,2048,4096] fp32
  const int*   qw   = (const int*)d_in[1];    // [11008,4096] int32 in [-8,7]
  const float* sc   = (const float*)d_in[2];  // [11008,32] fp32
  const float* bias = (const float*)d_in[3];  // [11008] fp32
  float* out = (float*)d_out;                 // [2,2048,11008] fp32

  bf16* wq = (bf16*)d_ws;
  bf16* xb = (bf16*)((char*)d_ws + (size_t)OUT_F * IN_F * sizeof(bf16));

  dequant_w_kernel<<<(OUT_F * IN_F / 8) / 256, 256, 0, stream>>>(qw, sc, wq);
  cast_x_kernel<<<(M_TOT * IN_F / 8) / 256, 256, 0, stream>>>(x, xb);

  dim3 grid(M_TOT / BM, OUT_F / BN);  // 32 x 43
  gemm_bt_bias_kernel<<<grid, 256, 0, stream>>>(xb, wq, bias, out);
}